// Round 10
// baseline (175.087 us; speedup 1.0000x reference)
//
#include <hip/hip_runtime.h>
#include <hip/hip_bf16.h>
#include <math.h>

#define DDIM 7168
#define NEXP 256
#define NGRP 8
#define TOPKG 4
#define TOPK 8
#define ROUTE_SCALE 2.5f

#define BM 128
#define BN 128
#define BK 64
#define KSPLIT 4
#define KPER (DDIM / KSPLIT)     // 1792
#define NSTEP (KPER / BK)        // 28
#define NKT (DDIM / BK)          // 112 global k-tiles
#define BT_ELEMS (BN * BK * 2)   // 16384 shorts = 32 KB per (kt, nh) tile

typedef __attribute__((ext_vector_type(8))) short bf16x8;
typedef __attribute__((ext_vector_type(4))) float f32x4;
typedef unsigned int u32;
typedef unsigned short ushort_t;

static __device__ __forceinline__ ushort_t bf16_rne(float f) {
    u32 b = __float_as_uint(f);
    u32 r = (b + 0x7fffu + ((b >> 16) & 1u)) >> 16;
    return (ushort_t)r;
}
static __device__ __forceinline__ float bf16_to_f32(ushort_t h) {
    return __uint_as_float(((u32)h) << 16);
}
// hi = bf16(f) via HW cvt; lo = bf16(f - hi)
static __device__ __forceinline__ void split_elem(float f, short& h, short& l) {
    union { __hip_bfloat16 b; short s; } cv;
    cv.b = __float2bfloat16(f);
    h = cv.s;
    float hf = __uint_as_float(((u32)(ushort_t)cv.s) << 16);
    cv.b = __float2bfloat16(f - hf);
    l = cv.s;
}

// ---------------------------------------------------------------------------
// Kernel 0: split w into hi/lo bf16, fragment-linear tiles per (kt, nh).
// Tile (32 KB): [split(2)][ks(2)][fn(8)][lane(64)][8 bf16]  — R7-proven.
// element = split of W[nh*128 + fn*16 + (lane&15)][kt*64 + ks*32 + (lane>>4)*8 + j]
// ---------------------------------------------------------------------------
__global__ __launch_bounds__(256) void wsplit_kernel(const float* __restrict__ w,
                                                     short* __restrict__ wsp)
{
    const int kt = blockIdx.x;      // 0..111
    const int e  = threadIdx.x;     // expert 0..255
    const float* wp = w + (size_t)e * DDIM + (size_t)kt * BK;
    const int nh = e >> 7, fn = (e >> 4) & 7, er = e & 15;
    short* tb = wsp + ((size_t)kt * 2 + nh) * BT_ELEMS;
    #pragma unroll
    for (int ks = 0; ks < 2; ks++) {
        #pragma unroll
        for (int jg = 0; jg < 4; jg++) {
            float f[8];
            *(float4*)&f[0] = *(const float4*)(wp + ks * 32 + jg * 8);
            *(float4*)&f[4] = *(const float4*)(wp + ks * 32 + jg * 8 + 4);
            ushort_t h[8], l[8];
            #pragma unroll
            for (int j = 0; j < 8; j++) {
                h[j] = bf16_rne(f[j]);
                l[j] = bf16_rne(f[j] - bf16_to_f32(h[j]));
            }
            const int lane = jg * 16 + er;
            *(uint4*)(tb + ((size_t)((0 * 2 + ks) * 8 + fn) * 64 + lane) * 8) = *(uint4*)h;
            *(uint4*)(tb + ((size_t)((1 * 2 + ks) * 8 + fn) * 64 + lane) * 8) = *(uint4*)l;
        }
    }
}

// ---------------------------------------------------------------------------
// Kernel 1: split-precision bf16 MFMA GEMM.
// grid = 512 blocks = 2/CU (the m97 implicit-overlap ingredient every
// 1-block/CU round lacked); 512 thr = 8 waves (4 wm x 2 wn), wave tile 32x64,
// BK=64 -> 48 MFMA/wave/step. LDS: 2 x 32 KB double-buffer.
// XCD-bijective: bid%8 = XCD -> (ksp,nh); each XCD's 64 blocks share one
// 896 KB w-slice (L2-resident).
// Sync: uniform `s_waitcnt vmcnt(8)` + lgkmcnt(0) + raw s_barrier per step.
// Ledger: body(st) issues STAGE_B(st+1)[4] then LOAD_A(st+1)[8]; at top of
// step st the youngest 12 = A(st)(8 youngest) + B(st)(next 4) -> all-but-8
// retires B(st) (own-wave chunk; barrier makes it block-wide). A(st) is
// covered by the compiler's register-dep wait at convert (vmcnt(4), one full
// step aged). WAR: STAGE_B(st+1) writes buf[p^1], last ds_read in step st-1
// and retired there by MFMA data deps before this step's barrier.
// No setprio (m190: hurts non-8-phase GEMM).
// ---------------------------------------------------------------------------
__global__ __launch_bounds__(512, 4) void gemm_split_kernel(
    const float* __restrict__ x, const short* __restrict__ wsp,
    float* __restrict__ part, int Btok)
{
    __shared__ short Blds[2][BT_ELEMS];   // 2 x 32 KB = 64 KB

    const int bid  = blockIdx.x;
    const int xcd  = bid & 7;             // hw XCD = bid % 8
    const int ksp  = xcd & 3;
    const int nh   = xcd >> 2;
    const int mt   = bid >> 3;            // 0..63
    const int m0   = mt * BM;
    const int kbase = ksp * KPER;
    const int t    = threadIdx.x;
    const int wid  = t >> 6, lane = t & 63;
    const int wm   = wid >> 1, wn = wid & 1;
    const int lr   = lane & 15, lg = lane >> 4;

    // B tile for step st: wsp[(( (ksp*NSTEP+st)*2 ) + nh) * BT_ELEMS]
    const short* wt0 = wsp + ((size_t)(ksp * NSTEP) * 2 + nh) * BT_ELEMS;
    // A: rows m0 + wm*32 + fm*16 + lr ; k = kbase + st*64 + ks*32 + lg*8
    const float* abase = x + (size_t)(m0 + wm * 32 + lr) * DDIM + kbase + lg * 8;

#define STAGE_B(stp, dst) do {                                                             \
        const short* gt_ = wt0 + (size_t)(stp) * 2 * BT_ELEMS;                             \
        _Pragma("unroll")                                                                  \
        for (int i_ = 0; i_ < 4; i_++) {                                                   \
            const int off_ = wid * 4096 + i_ * 1024;                                       \
            __builtin_amdgcn_global_load_lds(                                              \
                (const __attribute__((address_space(1))) u32*)((const char*)gt_ + off_ + lane * 16), \
                (__attribute__((address_space(3))) u32*)((char*)(dst) + off_),             \
                16, 0, 0);                                                                 \
        } } while (0)

#define LOAD_A(stp) do {                                                                   \
        _Pragma("unroll")                                                                  \
        for (int fm_ = 0; fm_ < 2; fm_++)                                                  \
            _Pragma("unroll")                                                              \
            for (int ks_ = 0; ks_ < 2; ks_++) {                                            \
                const float* ap_ = abase + (size_t)fm_ * 16 * DDIM + (size_t)(stp) * BK + ks_ * 32; \
                *(float4*)&a_cur[fm_][ks_][0] = *(const float4*)(ap_);                     \
                *(float4*)&a_cur[fm_][ks_][4] = *(const float4*)(ap_ + 4);                 \
            } } while (0)

    f32x4 acc[2][4];
    #pragma unroll
    for (int i = 0; i < 2; i++)
        #pragma unroll
        for (int j = 0; j < 4; j++) acc[i][j] = (f32x4){0.f, 0.f, 0.f, 0.f};

    float a_cur[2][2][8];   // A(st) floats, 1-step-ahead (32 VGPR)

    // ---- prologue: B(0) DMA + A(0) regs (order sets the vmcnt ledger) ----
    STAGE_B(0, &Blds[0][0]);
    LOAD_A(0);

    for (int st = 0; st < NSTEP; st++) {
        const int cur = st & 1;
        // B(st) resident after this (own chunk by vmcnt, block-wide by barrier)
        asm volatile("s_waitcnt vmcnt(8)" ::: "memory");
        asm volatile("s_waitcnt lgkmcnt(0)" ::: "memory");
        __builtin_amdgcn_s_barrier();

        // ---- issue B(st+1) DMA into the buffer read at step st-1 ----
        if (st + 1 < NSTEP) STAGE_B(st + 1, &Blds[cur ^ 1][0]);

        // ---- convert A(st) -> hi/lo fragments (compiler waits vmcnt(4)) ----
        bf16x8 ah[2][2], al[2][2];
        #pragma unroll
        for (int fm = 0; fm < 2; fm++)
            #pragma unroll
            for (int ks = 0; ks < 2; ks++) {
                union { bf16x8 v; short s[8]; } H, L;
                #pragma unroll
                for (int j = 0; j < 8; j++)
                    split_elem(a_cur[fm][ks][j], H.s[j], L.s[j]);
                ah[fm][ks] = H.v;
                al[fm][ks] = L.v;
            }

        // ---- issue A(st+1) loads (regs free; land during MFMAs) ----
        if (st + 1 < NSTEP) LOAD_A(st + 1);

        // ---- MFMA: C += Ah*Bh + Ah*Bl + Al*Bh  (48/wave/step) ----
        #pragma unroll
        for (int fn = 0; fn < 4; fn++) {
            #pragma unroll
            for (int ks = 0; ks < 2; ks++) {
                const bf16x8 bh = *(const bf16x8*)&Blds[cur][((size_t)((0 * 2 + ks) * 8 + wn * 4 + fn) * 64 + lane) * 8];
                const bf16x8 bl = *(const bf16x8*)&Blds[cur][((size_t)((1 * 2 + ks) * 8 + wn * 4 + fn) * 64 + lane) * 8];
                #pragma unroll
                for (int fm = 0; fm < 2; fm++) {
                    acc[fm][fn] = __builtin_amdgcn_mfma_f32_16x16x32_bf16(ah[fm][ks], bh, acc[fm][fn], 0, 0, 0);
                    acc[fm][fn] = __builtin_amdgcn_mfma_f32_16x16x32_bf16(ah[fm][ks], bl, acc[fm][fn], 0, 0, 0);
                    acc[fm][fn] = __builtin_amdgcn_mfma_f32_16x16x32_bf16(al[fm][ks], bh, acc[fm][fn], 0, 0, 0);
                }
            }
        }
    }
#undef STAGE_B
#undef LOAD_A

    // ---- epilogue: fp32 partials (C/D map: col=lane&15, row=(lane>>4)*4+reg) ----
    float* pp = part + (size_t)ksp * (size_t)Btok * NEXP;
    #pragma unroll
    for (int fm = 0; fm < 2; fm++) {
        const int row0 = m0 + wm * 32 + fm * 16 + lg * 4;
        #pragma unroll
        for (int fn = 0; fn < 4; fn++) {
            const int col = nh * 128 + wn * 64 + fn * 16 + lr;
            #pragma unroll
            for (int rr = 0; rr < 4; rr++)
                pp[(size_t)(row0 + rr) * NEXP + col] = acc[fm][fn][rr];
        }
    }
}

// ---------------------------------------------------------------------------
// Kernel 2: reduce split-K partials + sigmoid + full gating, one wave per row.
// (unchanged — proven)
// ---------------------------------------------------------------------------
__global__ __launch_bounds__(256) void gate_kernel(
    const float* __restrict__ part, const float* __restrict__ bias,
    float* __restrict__ out_w, float* __restrict__ out_i, int B)
{
    const int lane = threadIdx.x & 63;
    const int wid  = threadIdx.x >> 6;
    const int row  = blockIdx.x * 4 + wid;
    if (row >= B) return;

    const size_t plane = (size_t)B * NEXP;
    const float* pr = part + (size_t)row * NEXP + lane * 4;
    float4 v0 = *(const float4*)(pr);
    float4 v1 = *(const float4*)(pr + plane);
    float4 v2 = *(const float4*)(pr + 2 * plane);
    float4 v3 = *(const float4*)(pr + 3 * plane);
    float sc[4] = { v0.x + v1.x + v2.x + v3.x,
                    v0.y + v1.y + v2.y + v3.y,
                    v0.z + v1.z + v2.z + v3.z,
                    v0.w + v1.w + v2.w + v3.w };
    float4 bv = *(const float4*)(bias + lane * 4);
    const float bb[4] = { bv.x, bv.y, bv.z, bv.w };

    float so[4], sb[4];
    #pragma unroll
    for (int j = 0; j < 4; j++) {
        so[j] = 1.0f / (1.0f + expf(-sc[j]));
        sb[j] = so[j] + bb[j];
    }

    // ---- group scores: sum of top-2 of sb within each 32-expert group ----
    float m1 = sb[0], m2 = -INFINITY;
    #pragma unroll
    for (int j = 1; j < 4; j++) {
        if (sb[j] > m1)      { m2 = m1; m1 = sb[j]; }
        else if (sb[j] > m2) { m2 = sb[j]; }
    }
    #pragma unroll
    for (int m = 1; m <= 4; m <<= 1) {
        float o1 = __shfl_xor(m1, m);
        float o2 = __shfl_xor(m2, m);
        float hi = fmaxf(m1, o1);
        float lo = fminf(m1, o1);
        m1 = hi;
        m2 = fmaxf(lo, fmaxf(m2, o2));
    }
    float gscore = m1 + m2;
    int g = lane >> 3;

    // ---- top-4 groups (value desc, index asc) ----
    float gs[NGRP];
    #pragma unroll
    for (int gg = 0; gg < NGRP; gg++) gs[gg] = __shfl(gscore, gg * 8);
    int rank = 0;
    #pragma unroll
    for (int gg = 0; gg < NGRP; gg++) {
        if (gg == g) continue;
        if (gs[gg] > gs[g] || (gs[gg] == gs[g] && gg < g)) rank++;
    }
    const bool selg = (rank < TOPKG);
    float mv[4];
    #pragma unroll
    for (int j = 0; j < 4; j++) mv[j] = selg ? sb[j] : -INFINITY;

    // ---- iterative top-8 wave argmax (value desc, index asc) ----
    float wsel[TOPK];
    int   isel[TOPK];
    float wsum = 0.f;
    #pragma unroll
    for (int it = 0; it < TOPK; it++) {
        float v = mv[0]; int jj = 0;
        #pragma unroll
        for (int j = 1; j < 4; j++)
            if (mv[j] > v) { v = mv[j]; jj = j; }
        int gi = (lane << 2) | jj;
        #pragma unroll
        for (int m = 1; m < 64; m <<= 1) {
            float ov = __shfl_xor(v, m);
            int   oi = __shfl_xor(gi, m);
            if (ov > v || (ov == v && oi < gi)) { v = ov; gi = oi; }
        }
        int slot = gi & 3, src = gi >> 2;
        float cand = (slot == 0) ? so[0] : (slot == 1) ? so[1] : (slot == 2) ? so[2] : so[3];
        float sval = __shfl(cand, src);
        wsel[it] = sval; isel[it] = gi; wsum += sval;
        if (lane == src) mv[slot] = -INFINITY;
    }

    if (lane == 0) {
        float scl = ROUTE_SCALE / wsum;
        #pragma unroll
        for (int it = 0; it < TOPK; it++) {
            out_w[(size_t)row * TOPK + it] = wsel[it] * scl;
            out_i[(size_t)row * TOPK + it] = (float)isel[it];
        }
    }
}

extern "C" void kernel_launch(void* const* d_in, const int* in_sizes, int n_in,
                              void* d_out, int out_size, void* d_ws, size_t ws_size,
                              hipStream_t stream)
{
    const float* x    = (const float*)d_in[0];
    const float* w    = (const float*)d_in[1];
    const float* bias = (const float*)d_in[2];
    const int B = in_sizes[0] / DDIM;           // 8192

    // ws layout: [ part: 4 * B * 256 f32 = 32 MB ][ wsp: 112*2 tiles * 32 KB = 7.34 MB ]
    float* part = (float*)d_ws;
    short* wsp  = (short*)((char*)d_ws + (size_t)KSPLIT * B * NEXP * sizeof(float));

    float* out_w = (float*)d_out;
    float* out_i = out_w + (size_t)B * TOPK;

    hipLaunchKernelGGL(wsplit_kernel, dim3(NKT), dim3(256), 0, stream, w, wsp);
    hipLaunchKernelGGL(gemm_split_kernel, dim3((B / BM) * 2 * KSPLIT), dim3(512), 0, stream,
                       x, wsp, part, B);
    hipLaunchKernelGGL(gate_kernel, dim3((B + 3) / 4), dim3(256), 0, stream,
                       part, bias, out_w, out_i, B);
}